// Round 24
// baseline (20.782 us; speedup 1.0000x reference)
//
#include <hip/hip_runtime.h>
#include <hip/hip_bf16.h>

#define BS 512
#define MARGIN 0.5f
#define PLANE 262144  // 512*512
#define NZ 4          // K-split factor
#define KQ 128        // K per split

using short8 = __attribute__((ext_vector_type(8))) short;
using f32x4 = __attribute__((ext_vector_type(4))) float;

__device__ inline short bf16_rne(float x) {
    __hip_bfloat16 h = __float2bfloat16(x);
    return *(short*)&h;
}

// Kernel 1: K-split x4 partial-dot. Grid (16,16,4): z = K-quarter. Each block:
// own ballot compaction; 32x32 tile of raw bf16-MFMA dots over its K-quarter,
// written to plane z (compacted layout: rows = pos-rank; cols = pos-rank then
// npos+neg-rank). Per-quarter raw norms to nrmA/nrmC (benign dup writes).
// 512 active blocks at npos=256 -> 2 waves/CU.
__global__ __launch_bounds__(64) void kdistp(const float* __restrict__ pred,
                                             const int* __restrict__ target,
                                             float* __restrict__ pdot,
                                             float* __restrict__ nrmA,
                                             float* __restrict__ nrmC,
                                             int* __restrict__ counts) {
    const int lane = threadIdx.x;
    const int kh = blockIdx.z;
    __shared__ int plist[BS];
    __shared__ int rnk[BS];
    __shared__ int tgs[BS];

    int pbase = 0, nbase = 0;
    const unsigned long long below = (1ULL << lane) - 1ULL;
#pragma unroll
    for (int c = 0; c < 8; ++c) {
        const int idx = c * 64 + lane;
        const int tg = target[idx];
        const unsigned long long mp = __ballot(tg == 1);
        const int prk = pbase + __popcll(mp & below);
        const int nrk = nbase + __popcll((~mp) & below);
        tgs[idx] = tg;
        rnk[idx] = (tg == 1) ? prk : nrk;
        if (tg == 1) plist[prk] = idx;
        const int np = __popcll(mp);
        pbase += np;
        nbase += 64 - np;
    }
    const int npos = pbase;
    __syncthreads();

    if (blockIdx.x == 0 && blockIdx.y == 0 && kh == 0 && lane == 0) {
        counts[0] = npos;
        counts[1] = nbase;
    }

    const int r0 = blockIdx.y * 32;
    if (r0 >= npos) return;
    const int c0 = blockIdx.x * 32;
    const int rl = lane & 15;
    const int koff = (lane >> 4) * 8;
    const int kbase = kh * KQ;

    const int pr0 = min(r0 + rl, npos - 1);
    const int pr1 = min(r0 + 16 + rl, npos - 1);
    const float* A0 = pred + plist[pr0] * BS + kbase;
    const float* A1 = pred + plist[pr1] * BS + kbase;
    const float* B0 = pred + (c0 + rl) * BS + kbase;
    const float* B1 = pred + (c0 + 16 + rl) * BS + kbase;

    f32x4 acc00 = {0.f, 0.f, 0.f, 0.f};
    f32x4 acc01 = {0.f, 0.f, 0.f, 0.f};
    f32x4 acc10 = {0.f, 0.f, 0.f, 0.f};
    f32x4 acc11 = {0.f, 0.f, 0.f, 0.f};
    float na0 = 0.f, na1 = 0.f, nb0 = 0.f, nb1 = 0.f;

#pragma unroll
    for (int ks = 0; ks < KQ / 32; ++ks) {  // 4 k-steps of 32
        const int k = ks * 32 + koff;
        const f32x4 a0l = *(const f32x4*)(A0 + k);
        const f32x4 a0h = *(const f32x4*)(A0 + k + 4);
        const f32x4 a1l = *(const f32x4*)(A1 + k);
        const f32x4 a1h = *(const f32x4*)(A1 + k + 4);
        const f32x4 b0l = *(const f32x4*)(B0 + k);
        const f32x4 b0h = *(const f32x4*)(B0 + k + 4);
        const f32x4 b1l = *(const f32x4*)(B1 + k);
        const f32x4 b1h = *(const f32x4*)(B1 + k + 4);

        short8 sa0, sa1, sb0, sb1;
#pragma unroll
        for (int j = 0; j < 4; ++j) {
            na0 += a0l[j] * a0l[j] + a0h[j] * a0h[j];
            na1 += a1l[j] * a1l[j] + a1h[j] * a1h[j];
            nb0 += b0l[j] * b0l[j] + b0h[j] * b0h[j];
            nb1 += b1l[j] * b1l[j] + b1h[j] * b1h[j];
            sa0[j] = bf16_rne(a0l[j]); sa0[4 + j] = bf16_rne(a0h[j]);
            sa1[j] = bf16_rne(a1l[j]); sa1[4 + j] = bf16_rne(a1h[j]);
            sb0[j] = bf16_rne(b0l[j]); sb0[4 + j] = bf16_rne(b0h[j]);
            sb1[j] = bf16_rne(b1l[j]); sb1[4 + j] = bf16_rne(b1h[j]);
        }
        acc00 = __builtin_amdgcn_mfma_f32_16x16x32_bf16(sa0, sb0, acc00, 0, 0, 0);
        acc01 = __builtin_amdgcn_mfma_f32_16x16x32_bf16(sa0, sb1, acc01, 0, 0, 0);
        acc10 = __builtin_amdgcn_mfma_f32_16x16x32_bf16(sa1, sb0, acc10, 0, 0, 0);
        acc11 = __builtin_amdgcn_mfma_f32_16x16x32_bf16(sa1, sb1, acc11, 0, 0, 0);
    }

    na0 += __shfl_xor(na0, 16, 64); na0 += __shfl_xor(na0, 32, 64);
    na1 += __shfl_xor(na1, 16, 64); na1 += __shfl_xor(na1, 32, 64);
    nb0 += __shfl_xor(nb0, 16, 64); nb0 += __shfl_xor(nb0, 32, 64);
    nb1 += __shfl_xor(nb1, 16, 64); nb1 += __shfl_xor(nb1, 32, 64);

    float* pd = pdot + kh * PLANE;
    float* nA = nrmA + kh * 512;
    float* nC = nrmC + kh * 512;

    // per-quarter norm writes (duplicate identical writes across blocks: benign)
    if (lane < 16) {
        nA[r0 + lane] = na0;
        nA[r0 + 16 + lane] = na1;
        const int ca = c0 + lane;
        const int cca = (tgs[ca] == 1) ? rnk[ca] : npos + rnk[ca];
        nC[cca] = nb0;
        const int cb = c0 + 16 + lane;
        const int ccb = (tgs[cb] == 1) ? rnk[cb] : npos + rnk[cb];
        nC[ccb] = nb1;
    }

    // C/D layout: col = lane&15, row = (lane>>4)*4 + reg  [m89]
    const int rbase = (lane >> 4) * 4;
#pragma unroll
    for (int fr = 0; fr < 2; ++fr) {
#pragma unroll
        for (int fc = 0; fc < 2; ++fc) {
            f32x4 v = (fr == 0) ? (fc == 0 ? acc00 : acc01) : (fc == 0 ? acc10 : acc11);
            const int col = c0 + fc * 16 + rl;
            const int ccol = (tgs[col] == 1) ? rnk[col] : npos + rnk[col];
#pragma unroll
            for (int r = 0; r < 4; ++r) {
                const int rowp = r0 + fr * 16 + rbase + r;  // pos-rank row
                pd[rowp * BS + ccol] = v[r];                // raw partial dot
            }
        }
    }
}

// Kernel 2: block b = pos-rank anchor. Finalize (sum 4 K-quarters, scale by
// inv-norms, sqrt, +MARGIN for pos cols) then hinge. Coalesced loads only.
__global__ __launch_bounds__(256) void ktriplet(const float* __restrict__ pdot,
                                                const float* __restrict__ nrmA,
                                                const float* __restrict__ nrmC,
                                                const int* __restrict__ counts,
                                                float* __restrict__ psum,
                                                float* __restrict__ pcnt) {
    const int b = blockIdx.x;
    const int tid = threadIdx.x;
    const int npos = counts[0];
    if (b >= npos) {
        if (tid == 0) { psum[b] = 0.f; pcnt[b] = 0.f; }
        return;
    }
    const int nneg = counts[1];
    const int lane = tid & 63;
    const int w = tid >> 6;
    __shared__ float sbuf[4];
    __shared__ float cbuf[4];

    const float* dr = pdot + b * BS;
    float nAb = 0.f;
#pragma unroll
    for (int z = 0; z < NZ; ++z) nAb += nrmA[z * 512 + b];
    const float ia = 1.0f / fmaxf(sqrtf(nAb), 1e-10f);

    auto dcol = [&](int cc) -> float {
        float dot = 0.f, nc = 0.f;
#pragma unroll
        for (int z = 0; z < NZ; ++z) {
            dot += dr[z * PLANE + cc];
            nc += nrmC[z * 512 + cc];
        }
        const float ic = 1.0f / fmaxf(sqrtf(nc), 1e-10f);
        return sqrtf(fmaxf(2.0f - 2.0f * dot * ia * ic, 0.0f));
    };

    // k-role: coalesced from [npos + tid]
    const float bv0 = (tid < nneg) ? dcol(npos + tid) : 1e30f;
    const float bv1 = (tid + 256 < nneg) ? dcol(npos + 256 + tid) : 1e30f;

    // j-role: wave w owns chunks w and w+4; margin folded here
    const int ja = w * 64 + lane;
    const int jb = (w + 4) * 64 + lane;
    const float av0 = (ja < npos && ja != b) ? dcol(ja) + MARGIN : -1e9f;
    const float av1 = (jb < npos && jb != b) ? dcol(jb) + MARGIN : -1e9f;

    float sum = 0.f;
    unsigned int cw = 0;

#define HINGE(TJ, BK)                                       \
    do {                                                    \
        const float v_ = (TJ) - (BK);                       \
        sum += fmaxf(v_, 0.f);                              \
        cw += (unsigned int)__popcll(__ballot(v_ > 0.f));   \
    } while (0)

    if (nneg > 256) {  // uniform rare path
        if (w * 64 < npos) {
#pragma unroll 8
            for (int jj = 0; jj < 64; ++jj) {
                const float tj = __int_as_float(
                    __builtin_amdgcn_readlane(__float_as_int(av0), jj));
                HINGE(tj, bv0); HINGE(tj, bv1);
            }
        }
        if ((w + 4) * 64 < npos) {
#pragma unroll 8
            for (int jj = 0; jj < 64; ++jj) {
                const float tj = __int_as_float(
                    __builtin_amdgcn_readlane(__float_as_int(av1), jj));
                HINGE(tj, bv0); HINGE(tj, bv1);
            }
        }
    } else {  // typical: nneg <= 256
        if (w * 64 < npos) {
#pragma unroll 8
            for (int jj = 0; jj < 64; ++jj) {
                const float tj = __int_as_float(
                    __builtin_amdgcn_readlane(__float_as_int(av0), jj));
                HINGE(tj, bv0);
            }
        }
        if ((w + 4) * 64 < npos) {
#pragma unroll 8
            for (int jj = 0; jj < 64; ++jj) {
                const float tj = __int_as_float(
                    __builtin_amdgcn_readlane(__float_as_int(av1), jj));
                HINGE(tj, bv0);
            }
        }
    }
#undef HINGE

    float wsm = sum;
#pragma unroll
    for (int o = 32; o > 0; o >>= 1) wsm += __shfl_xor(wsm, o, 64);
    if (lane == 0) { sbuf[w] = wsm; cbuf[w] = (float)cw; }
    __syncthreads();
    if (tid == 0) {
        psum[b] = (sbuf[0] + sbuf[1]) + (sbuf[2] + sbuf[3]);
        pcnt[b] = (cbuf[0] + cbuf[1]) + (cbuf[2] + cbuf[3]);
    }
}

// Kernel 3: one wave reduces 512 partial slots + divides. Fixed order.
__global__ __launch_bounds__(64) void kfinal(const float* __restrict__ psum,
                                             const float* __restrict__ pcnt,
                                             float* __restrict__ out) {
    const int lane = threadIdx.x;
    float s = 0.f, c = 0.f;
#pragma unroll
    for (int r = 0; r < 8; ++r) {
        s += psum[r * 64 + lane];
        c += pcnt[r * 64 + lane];
    }
#pragma unroll
    for (int o = 32; o > 0; o >>= 1) {
        s += __shfl_xor(s, o, 64);
        c += __shfl_xor(c, o, 64);
    }
    if (lane == 0) out[0] = s / (c + 1e-7f);
}

extern "C" void kernel_launch(void* const* d_in, const int* in_sizes, int n_in,
                              void* d_out, int out_size, void* d_ws, size_t ws_size,
                              hipStream_t stream) {
    const float* pred = (const float*)d_in[0];
    const int* target = (const int*)d_in[1];
    float* out = (float*)d_out;
    char* base = (char*)d_ws;

    float* pdot = (float*)base;                     // 4 MB: four K-quarter planes
    float* nrmA = (float*)(base + 4194304);         // 8 KB (4 x 512)
    float* nrmC = (float*)(base + 4202496);         // 8 KB (4 x 512)
    float* psum = (float*)(base + 4210688);         // 2 KB
    float* pcnt = (float*)(base + 4212736);         // 2 KB
    int* counts = (int*)(base + 4214784);           // 8 B

    dim3 gb(16, 16, NZ);  // 32x32 tiles x 4 K-quarters -> 512 active blocks
    kdistp<<<gb, 64, 0, stream>>>(pred, target, pdot, nrmA, nrmC, counts);
    ktriplet<<<512, 256, 0, stream>>>(pdot, nrmA, nrmC, counts, psum, pcnt);
    kfinal<<<1, 64, 0, stream>>>(psum, pcnt, out);
}

// Round 25
// 19.887 us; speedup vs baseline: 1.0450x; 1.0450x over previous
//
#include <hip/hip_runtime.h>
#include <hip/hip_bf16.h>

#define BS 512
#define MARGIN 0.5f
#define PLANE 262144  // 512*512

using short8 = __attribute__((ext_vector_type(8))) short;
using f32x4 = __attribute__((ext_vector_type(4))) float;

__device__ inline short bf16_rne(float x) {
    __hip_bfloat16 h = __float2bfloat16(x);
    return *(short*)&h;
}

// Kernel 1: K-split x2 partial-dot. Grid (16,16,2): z = K-half. Each block:
// own ballot compaction; 32x32 tile of raw bf16-MFMA dots over its K-half,
// written to plane z in compacted layout (rows = pos-rank; cols = pos-rank
// then npos+neg-rank). Per-half raw norms to nrmA/nrmC (benign dup writes).
// 256 active blocks at npos=256 -> full CU coverage. [R21 optimum: 19.95us]
__global__ __launch_bounds__(64) void kdistp(const float* __restrict__ pred,
                                             const int* __restrict__ target,
                                             float* __restrict__ pdot,
                                             float* __restrict__ nrmA,
                                             float* __restrict__ nrmC,
                                             int* __restrict__ counts) {
    const int lane = threadIdx.x;
    const int kh = blockIdx.z;
    __shared__ int plist[BS];
    __shared__ int rnk[BS];
    __shared__ int tgs[BS];

    int pbase = 0, nbase = 0;
    const unsigned long long below = (1ULL << lane) - 1ULL;
#pragma unroll
    for (int c = 0; c < 8; ++c) {
        const int idx = c * 64 + lane;
        const int tg = target[idx];
        const unsigned long long mp = __ballot(tg == 1);
        const int prk = pbase + __popcll(mp & below);
        const int nrk = nbase + __popcll((~mp) & below);
        tgs[idx] = tg;
        rnk[idx] = (tg == 1) ? prk : nrk;
        if (tg == 1) plist[prk] = idx;
        const int np = __popcll(mp);
        pbase += np;
        nbase += 64 - np;
    }
    const int npos = pbase;
    __syncthreads();

    if (blockIdx.x == 0 && blockIdx.y == 0 && kh == 0 && lane == 0) {
        counts[0] = npos;
        counts[1] = nbase;
    }

    const int r0 = blockIdx.y * 32;
    if (r0 >= npos) return;
    const int c0 = blockIdx.x * 32;
    const int rl = lane & 15;
    const int koff = (lane >> 4) * 8;
    const int kbase = kh * 256;

    const int pr0 = min(r0 + rl, npos - 1);
    const int pr1 = min(r0 + 16 + rl, npos - 1);
    const float* A0 = pred + plist[pr0] * BS + kbase;
    const float* A1 = pred + plist[pr1] * BS + kbase;
    const float* B0 = pred + (c0 + rl) * BS + kbase;
    const float* B1 = pred + (c0 + 16 + rl) * BS + kbase;

    f32x4 acc00 = {0.f, 0.f, 0.f, 0.f};
    f32x4 acc01 = {0.f, 0.f, 0.f, 0.f};
    f32x4 acc10 = {0.f, 0.f, 0.f, 0.f};
    f32x4 acc11 = {0.f, 0.f, 0.f, 0.f};
    float na0 = 0.f, na1 = 0.f, nb0 = 0.f, nb1 = 0.f;

#pragma unroll 4
    for (int ks = 0; ks < 8; ++ks) {  // half-K: 8 x 32
        const int k = ks * 32 + koff;
        const f32x4 a0l = *(const f32x4*)(A0 + k);
        const f32x4 a0h = *(const f32x4*)(A0 + k + 4);
        const f32x4 a1l = *(const f32x4*)(A1 + k);
        const f32x4 a1h = *(const f32x4*)(A1 + k + 4);
        const f32x4 b0l = *(const f32x4*)(B0 + k);
        const f32x4 b0h = *(const f32x4*)(B0 + k + 4);
        const f32x4 b1l = *(const f32x4*)(B1 + k);
        const f32x4 b1h = *(const f32x4*)(B1 + k + 4);

        short8 sa0, sa1, sb0, sb1;
#pragma unroll
        for (int j = 0; j < 4; ++j) {
            na0 += a0l[j] * a0l[j] + a0h[j] * a0h[j];
            na1 += a1l[j] * a1l[j] + a1h[j] * a1h[j];
            nb0 += b0l[j] * b0l[j] + b0h[j] * b0h[j];
            nb1 += b1l[j] * b1l[j] + b1h[j] * b1h[j];
            sa0[j] = bf16_rne(a0l[j]); sa0[4 + j] = bf16_rne(a0h[j]);
            sa1[j] = bf16_rne(a1l[j]); sa1[4 + j] = bf16_rne(a1h[j]);
            sb0[j] = bf16_rne(b0l[j]); sb0[4 + j] = bf16_rne(b0h[j]);
            sb1[j] = bf16_rne(b1l[j]); sb1[4 + j] = bf16_rne(b1h[j]);
        }
        acc00 = __builtin_amdgcn_mfma_f32_16x16x32_bf16(sa0, sb0, acc00, 0, 0, 0);
        acc01 = __builtin_amdgcn_mfma_f32_16x16x32_bf16(sa0, sb1, acc01, 0, 0, 0);
        acc10 = __builtin_amdgcn_mfma_f32_16x16x32_bf16(sa1, sb0, acc10, 0, 0, 0);
        acc11 = __builtin_amdgcn_mfma_f32_16x16x32_bf16(sa1, sb1, acc11, 0, 0, 0);
    }

    na0 += __shfl_xor(na0, 16, 64); na0 += __shfl_xor(na0, 32, 64);
    na1 += __shfl_xor(na1, 16, 64); na1 += __shfl_xor(na1, 32, 64);
    nb0 += __shfl_xor(nb0, 16, 64); nb0 += __shfl_xor(nb0, 32, 64);
    nb1 += __shfl_xor(nb1, 16, 64); nb1 += __shfl_xor(nb1, 32, 64);

    float* pd = pdot + kh * PLANE;
    float* nA = nrmA + kh * 512;
    float* nC = nrmC + kh * 512;

    // per-half norm writes (duplicate identical writes across blocks: benign)
    if (lane < 16) {
        nA[r0 + lane] = na0;
        nA[r0 + 16 + lane] = na1;
        const int ca = c0 + lane;
        const int cca = (tgs[ca] == 1) ? rnk[ca] : npos + rnk[ca];
        nC[cca] = nb0;
        const int cb = c0 + 16 + lane;
        const int ccb = (tgs[cb] == 1) ? rnk[cb] : npos + rnk[cb];
        nC[ccb] = nb1;
    }

    // C/D layout: col = lane&15, row = (lane>>4)*4 + reg  [m89]
    const int rbase = (lane >> 4) * 4;
#pragma unroll
    for (int fr = 0; fr < 2; ++fr) {
#pragma unroll
        for (int fc = 0; fc < 2; ++fc) {
            f32x4 v = (fr == 0) ? (fc == 0 ? acc00 : acc01) : (fc == 0 ? acc10 : acc11);
            const int col = c0 + fc * 16 + rl;
            const int ccol = (tgs[col] == 1) ? rnk[col] : npos + rnk[col];
#pragma unroll
            for (int r = 0; r < 4; ++r) {
                const int rowp = r0 + fr * 16 + rbase + r;  // pos-rank row
                pd[rowp * BS + ccol] = v[r];                // raw partial dot
            }
        }
    }
}

// Kernel 2: block b = pos-rank anchor. Finalize (sum K-halves, scale by
// inv-norms, sqrt, +MARGIN for pos cols) then hinge. Coalesced loads only.
__global__ __launch_bounds__(256) void ktriplet(const float* __restrict__ pdot,
                                                const float* __restrict__ nrmA,
                                                const float* __restrict__ nrmC,
                                                const int* __restrict__ counts,
                                                float* __restrict__ psum,
                                                float* __restrict__ pcnt) {
    const int b = blockIdx.x;
    const int tid = threadIdx.x;
    const int npos = counts[0];
    if (b >= npos) {
        if (tid == 0) { psum[b] = 0.f; pcnt[b] = 0.f; }
        return;
    }
    const int nneg = counts[1];
    const int lane = tid & 63;
    const int w = tid >> 6;
    __shared__ float sbuf[4];
    __shared__ float cbuf[4];

    const float* d0 = pdot + b * BS;
    const float* d1 = pdot + PLANE + b * BS;
    const float nAb = nrmA[b] + nrmA[512 + b];
    const float ia = 1.0f / fmaxf(sqrtf(nAb), 1e-10f);

    auto dcol = [&](int cc) -> float {
        const float dot = d0[cc] + d1[cc];
        const float nc = nrmC[cc] + nrmC[512 + cc];
        const float ic = 1.0f / fmaxf(sqrtf(nc), 1e-10f);
        return sqrtf(fmaxf(2.0f - 2.0f * dot * ia * ic, 0.0f));
    };

    // k-role: coalesced from [npos + tid]
    const float bv0 = (tid < nneg) ? dcol(npos + tid) : 1e30f;
    const float bv1 = (tid + 256 < nneg) ? dcol(npos + 256 + tid) : 1e30f;

    // j-role: wave w owns chunks w and w+4; margin folded here
    const int ja = w * 64 + lane;
    const int jb = (w + 4) * 64 + lane;
    const float av0 = (ja < npos && ja != b) ? dcol(ja) + MARGIN : -1e9f;
    const float av1 = (jb < npos && jb != b) ? dcol(jb) + MARGIN : -1e9f;

    float sum = 0.f;
    unsigned int cw = 0;

#define HINGE(TJ, BK)                                       \
    do {                                                    \
        const float v_ = (TJ) - (BK);                       \
        sum += fmaxf(v_, 0.f);                              \
        cw += (unsigned int)__popcll(__ballot(v_ > 0.f));   \
    } while (0)

    if (nneg > 256) {  // uniform rare path
        if (w * 64 < npos) {
#pragma unroll 8
            for (int jj = 0; jj < 64; ++jj) {
                const float tj = __int_as_float(
                    __builtin_amdgcn_readlane(__float_as_int(av0), jj));
                HINGE(tj, bv0); HINGE(tj, bv1);
            }
        }
        if ((w + 4) * 64 < npos) {
#pragma unroll 8
            for (int jj = 0; jj < 64; ++jj) {
                const float tj = __int_as_float(
                    __builtin_amdgcn_readlane(__float_as_int(av1), jj));
                HINGE(tj, bv0); HINGE(tj, bv1);
            }
        }
    } else {  // typical: nneg <= 256
        if (w * 64 < npos) {
#pragma unroll 8
            for (int jj = 0; jj < 64; ++jj) {
                const float tj = __int_as_float(
                    __builtin_amdgcn_readlane(__float_as_int(av0), jj));
                HINGE(tj, bv0);
            }
        }
        if ((w + 4) * 64 < npos) {
#pragma unroll 8
            for (int jj = 0; jj < 64; ++jj) {
                const float tj = __int_as_float(
                    __builtin_amdgcn_readlane(__float_as_int(av1), jj));
                HINGE(tj, bv0);
            }
        }
    }
#undef HINGE

    float wsm = sum;
#pragma unroll
    for (int o = 32; o > 0; o >>= 1) wsm += __shfl_xor(wsm, o, 64);
    if (lane == 0) { sbuf[w] = wsm; cbuf[w] = (float)cw; }
    __syncthreads();
    if (tid == 0) {
        psum[b] = (sbuf[0] + sbuf[1]) + (sbuf[2] + sbuf[3]);
        pcnt[b] = (cbuf[0] + cbuf[1]) + (cbuf[2] + cbuf[3]);
    }
}

// Kernel 3: one wave reduces 512 partial slots + divides. Fixed order.
__global__ __launch_bounds__(64) void kfinal(const float* __restrict__ psum,
                                             const float* __restrict__ pcnt,
                                             float* __restrict__ out) {
    const int lane = threadIdx.x;
    float s = 0.f, c = 0.f;
#pragma unroll
    for (int r = 0; r < 8; ++r) {
        s += psum[r * 64 + lane];
        c += pcnt[r * 64 + lane];
    }
#pragma unroll
    for (int o = 32; o > 0; o >>= 1) {
        s += __shfl_xor(s, o, 64);
        c += __shfl_xor(c, o, 64);
    }
    if (lane == 0) out[0] = s / (c + 1e-7f);
}

extern "C" void kernel_launch(void* const* d_in, const int* in_sizes, int n_in,
                              void* d_out, int out_size, void* d_ws, size_t ws_size,
                              hipStream_t stream) {
    const float* pred = (const float*)d_in[0];
    const int* target = (const int*)d_in[1];
    float* out = (float*)d_out;
    char* base = (char*)d_ws;

    float* pdot = (float*)base;                     // 2 MB: two K-half planes
    float* nrmA = (float*)(base + 2097152);         // 4 KB (2 x 512)
    float* nrmC = (float*)(base + 2101248);         // 4 KB (2 x 512)
    float* psum = (float*)(base + 2105344);         // 2 KB
    float* pcnt = (float*)(base + 2107392);         // 2 KB
    int* counts = (int*)(base + 2109440);           // 8 B

    dim3 gb(16, 16, 2);  // 32x32 tiles x 2 K-halves -> 256 active blocks
    kdistp<<<gb, 64, 0, stream>>>(pred, target, pdot, nrmA, nrmC, counts);
    ktriplet<<<512, 256, 0, stream>>>(pdot, nrmA, nrmC, counts, psum, pcnt);
    kfinal<<<1, 64, 0, stream>>>(psum, pcnt, out);
}